// Round 2
// baseline (197.504 us; speedup 1.0000x reference)
//
#include <hip/hip_runtime.h>

typedef unsigned short ushort_t;
typedef __attribute__((ext_vector_type(8)))  short  short8;
typedef __attribute__((ext_vector_type(8)))  ushort_t ushort8;
typedef __attribute__((ext_vector_type(16))) float  f32x16;

#define HWPX 16384
#define EPSV 0.001f

__device__ __forceinline__ ushort_t f2bf(float f) {
    unsigned u = __builtin_bit_cast(unsigned, f);
    unsigned r = u + 0x7FFFu + ((u >> 16) & 1u);   // round-to-nearest-even
    return (ushort_t)(r >> 16);
}

__device__ __forceinline__ unsigned cvt_pk(float a, float b) {
    unsigned r;
    asm("v_cvt_pk_bf16_f32 %0, %1, %2" : "=v"(r) : "v"(a), "v"(b));
    return r;   // lo = bf16(a), hi = bf16(b)
}

// ---------------- Pass 1: per-group mean + raw second moments -------------
// grid 512 = n(8) x g(8) x q(8); block 512 (8 waves). Each block: one group's
// channels (32) over a 2048-pixel slice. cov via rank-k MFMA (frag as A and B).
// XBF: also emit x_bf[n][px][c] (bf16, pixel-major) via per-wave LDS transpose.
template<bool XBF>
__global__ __launch_bounds__(512) void k_stats(const float* __restrict__ x,
                                               float* __restrict__ part,
                                               ushort_t* __restrict__ xb) {
    __shared__ ushort_t tile[8][32][16];   // per-wave 32c x 16px transpose buffer
    int b = blockIdx.x;
    int n = b >> 6, g = (b >> 3) & 7, q = b & 7;
    int t = threadIdx.x, w = t >> 6, l = t & 63;
    int lo = l & 31, hi = l >> 5;
    int rpx = l & 15, cg = l >> 4;         // readback role: (pixel, c-group-of-8)

    const float* xg = x + ((size_t)(n * 256 + g * 32 + lo)) * HWPX;
    int pxbase = q * 2048 + w * 256 + hi * 8;

    f32x16 acc = {};
    float sm = 0.f;
    #pragma unroll 4
    for (int it = 0; it < 16; ++it) {
        const float* p = xg + pxbase + it * 16;
        float4 v0 = *(const float4*)p;
        float4 v1 = *(const float4*)(p + 4);
        sm += v0.x + v0.y + v0.z + v0.w + v1.x + v1.y + v1.z + v1.w;
        uint4 uu;
        uu.x = cvt_pk(v0.x, v0.y);
        uu.y = cvt_pk(v0.z, v0.w);
        uu.z = cvt_pk(v1.x, v1.y);
        uu.w = cvt_pk(v1.z, v1.w);
        short8 f = __builtin_bit_cast(short8, uu);
        acc = __builtin_amdgcn_mfma_f32_32x32x16_bf16(f, f, acc, 0, 0, 0);
        if (XBF) {
            // lane holds 16 px (bf16) of channel lo -> write row, read column
            *(ushort8*)&tile[w][lo][hi * 8] = __builtin_bit_cast(ushort8, uu);
            asm volatile("s_waitcnt lgkmcnt(0)" ::: "memory");
            __builtin_amdgcn_sched_barrier(0);
            ushort8 o;
            #pragma unroll
            for (int j = 0; j < 8; ++j) o[j] = tile[w][cg * 8 + j][rpx];
            int px = q * 2048 + w * 256 + it * 16 + rpx;
            *(ushort8*)(xb + (((size_t)n * HWPX + px) << 8) + g * 32 + cg * 8) = o;
            __builtin_amdgcn_sched_barrier(0);
        }
    }

    __shared__ float redc[8][1024];
    __shared__ float redm[8][64];
    #pragma unroll
    for (int r = 0; r < 16; ++r) redc[w][l * 16 + r] = acc[r];
    redm[w][l] = sm;
    __syncthreads();

    for (int i = t; i < 1024; i += 512) {
        float v = 0.f;
        #pragma unroll
        for (int ww = 0; ww < 8; ++ww) v += redc[ww][i];
        int ll = i >> 4, r = i & 15;
        int row = (r & 3) + 8 * (r >> 2) + 4 * (ll >> 5);   // C/D layout 32x32 (m74/m101)
        int col = ll & 31;
        part[(size_t)b * 1056 + row * 32 + col] = v;
    }
    if (t < 32) {
        float v = 0.f;
        #pragma unroll
        for (int ww = 0; ww < 8; ++ww) v += redm[ww][t] + redm[ww][t + 32];
        part[(size_t)b * 1056 + 1024 + t] = v;
    }
}

// ---------------- Pass 2: reduce, cov, cholesky, L^{-1} -------------------
__global__ __launch_bounds__(64) void k_chol(const float* __restrict__ part,
                                             float* __restrict__ S,
                                             float* __restrict__ meanw) {
    int bg = blockIdx.x;
    int t = threadIdx.x;
    __shared__ float cov[1024];
    __shared__ float sums[32];
    __shared__ float A[32][33];
    __shared__ float Sl[32][33];

    for (int i = t; i < 1024; i += 64) {
        float v = 0.f;
        for (int q = 0; q < 8; ++q) v += part[(size_t)(bg * 8 + q) * 1056 + i];
        cov[i] = v;
    }
    if (t < 32) {
        float v = 0.f;
        for (int q = 0; q < 8; ++q) v += part[(size_t)(bg * 8 + q) * 1056 + 1024 + t];
        sums[t] = v;
    }
    __syncthreads();

    const float invHW = 1.0f / (float)HWPX;
    for (int i = t; i < 1024; i += 64) {
        int r = i >> 5, c = i & 31;
        float mr = sums[r] * invHW, mc = sums[c] * invHW;
        float cv = (cov[i] * invHW - mr * mc) * (1.0f - EPSV) + ((r == c) ? EPSV : 0.f);
        A[r][c] = cv;
    }
    __syncthreads();

    for (int k = 0; k < 32; ++k) {
        if (t == k) A[k][k] = sqrtf(A[k][k]);
        __syncthreads();
        if (t > k && t < 32) A[t][k] = A[t][k] / A[k][k];
        __syncthreads();
        if (t > k && t < 32) {
            float lik = A[t][k];
            for (int j = k + 1; j <= t; ++j) A[t][j] -= lik * A[j][k];
        }
        __syncthreads();
    }

    if (t < 32) {
        int c = t;
        for (int i = 0; i < c; ++i) Sl[i][c] = 0.f;
        Sl[c][c] = 1.0f / A[c][c];
        for (int i = c + 1; i < 32; ++i) {
            float s = 0.f;
            for (int j = c; j < i; ++j) s += A[i][j] * Sl[j][c];
            Sl[i][c] = -s / A[i][i];
        }
    }
    __syncthreads();

    for (int i = t; i < 1024; i += 64) S[(size_t)bg * 1024 + i] = Sl[i >> 5][i & 31];
    if (t < 32) meanw[bg * 32 + t] = sums[t] * invHW;
}

// ---------------- Pass 3: compose M = (conv_w + K^T) * S  -----------------
__global__ __launch_bounds__(256) void k_compose(const float* __restrict__ conv_w,
                                                 const float* __restrict__ EK,
                                                 const int* __restrict__ cls_arr,
                                                 const float* __restrict__ S,
                                                 const float* __restrict__ meanw,
                                                 ushort_t* __restrict__ M_bf,
                                                 float* __restrict__ bp) {
    int bid = blockIdx.x;
    int n = bid >> 3, g = bid & 7;
    int d = threadIdx.x;
    __shared__ float Sl[1024];
    __shared__ float ml[32];
    for (int i = d; i < 1024; i += 256) Sl[i] = S[(size_t)bid * 1024 + i];
    if (d < 32) ml[d] = meanw[bid * 32 + d];
    __syncthreads();

    int cls = cls_arr[n];
    float a[32];
    #pragma unroll
    for (int c = 0; c < 32; ++c)
        a[c] = conv_w[d * 256 + g * 32 + c] +
               EK[(size_t)cls * 65536 + (size_t)(g * 32 + c) * 256 + d];

    float bpv = 0.f;
    ushort8 pk[4];
    #pragma unroll
    for (int cp = 0; cp < 32; ++cp) {
        float m = 0.f;
        #pragma unroll
        for (int c = cp; c < 32; ++c) m += a[c] * Sl[c * 32 + cp];  // S lower-tri
        bpv += m * ml[cp];
        pk[cp >> 3][cp & 7] = f2bf(m);
    }
    ushort_t* dst = M_bf + ((size_t)(n * 256 + d)) * 256 + g * 32;
    #pragma unroll
    for (int k = 0; k < 4; ++k) *(ushort8*)(dst + k * 8) = pk[k];
    bp[(size_t)(n * 8 + g) * 256 + d] = bpv;
}

// ---------------- Pass 4: bias' = conv_b + eb - M*mean ---------------------
__global__ __launch_bounds__(256) void k_bias(const float* __restrict__ conv_b,
                                              const float* __restrict__ EB,
                                              const int* __restrict__ cls_arr,
                                              const float* __restrict__ bp,
                                              float* __restrict__ bias) {
    int n = blockIdx.x, d = threadIdx.x;
    int cls = cls_arr[n];
    float v = conv_b[d] + EB[cls * 256 + d];
    #pragma unroll
    for (int g = 0; g < 8; ++g) v -= bp[(size_t)(n * 8 + g) * 256 + d];
    bias[n * 256 + d] = v;
}

// ---------------- Pass 5 (fast): out = M_bf * x_bf + bias ------------------
// grid 1024 = n(8) x ptile(128, 128 px each); block 512 (8 waves, wave = 32 d).
// A-frags preloaded to regs; B-frags are direct 16B loads from px-major x_bf.
__global__ __launch_bounds__(512) void k_gemm_fast(const ushort_t* __restrict__ xb,
                                                   const ushort_t* __restrict__ M_bf,
                                                   const float* __restrict__ bias,
                                                   float* __restrict__ out) {
    int bid = blockIdx.x;
    int n = bid >> 7, pt = bid & 127;
    int px0 = pt * 128;
    int t = threadIdx.x, w = t >> 6, l = t & 63, lo = l & 31, hi = l >> 5;
    int dblk = w * 32;

    const ushort_t* Mrow = M_bf + ((size_t)(n * 256 + dblk + lo)) * 256;
    short8 a[16];
    #pragma unroll
    for (int ks = 0; ks < 16; ++ks)
        a[ks] = *(const short8*)(Mrow + ks * 16 + hi * 8);

    float bsv[16];
    int rows[16];
    #pragma unroll
    for (int r = 0; r < 16; ++r) {
        rows[r] = dblk + (r & 3) + 8 * (r >> 2) + 4 * hi;   // C/D layout (m74/m101)
        bsv[r] = bias[n * 256 + rows[r]];
    }

    const ushort_t* xbn = xb + (((size_t)n * HWPX) << 8);
    #pragma unroll 1
    for (int g4 = 0; g4 < 4; ++g4) {
        int pxl = px0 + g4 * 32 + lo;
        const ushort_t* xc = xbn + ((size_t)pxl << 8);
        f32x16 acc = {};
        #pragma unroll
        for (int ks = 0; ks < 16; ++ks) {
            short8 bfrag = *(const short8*)(xc + ks * 16 + hi * 8);
            acc = __builtin_amdgcn_mfma_f32_32x32x16_bf16(a[ks], bfrag, acc, 0, 0, 0);
        }
        #pragma unroll
        for (int r = 0; r < 16; ++r) {
            size_t o = ((size_t)(n * 256 + rows[r])) * HWPX + pxl;
            out[o] = acc[r] + bsv[r];
        }
    }
}

// ---------------- Pass 5 (fallback): out = M_bf * x(fp32) + bias -----------
__global__ __launch_bounds__(512) void k_gemm_fb(const float* __restrict__ x,
                                                 const ushort_t* __restrict__ M_bf,
                                                 const float* __restrict__ bias,
                                                 float* __restrict__ out) {
    int bid = blockIdx.x;
    int n = bid >> 8, pt = bid & 255;
    int px0 = pt * 64;
    int t = threadIdx.x, w = t >> 6, l = t & 63, lo = l & 31, hi = l >> 5;
    int dblk = w * 32;

    const ushort_t* Mrow = M_bf + ((size_t)(n * 256 + dblk + lo)) * 256;
    const float* xn = x + (size_t)n * 256 * HWPX;

    f32x16 acc0 = {}, acc1 = {};
    for (int ks = 0; ks < 16; ++ks) {
        int c0 = ks * 16 + hi * 8;
        short8 afrag = *(const short8*)(Mrow + c0);
        const float* xc = xn + (size_t)c0 * HWPX + px0 + lo;
        float b0[8], b1[8];
        #pragma unroll
        for (int bb = 0; bb < 8; ++bb) {
            b0[bb] = xc[(size_t)bb * HWPX];
            b1[bb] = xc[(size_t)bb * HWPX + 32];
        }
        short8 f0, f1;
        #pragma unroll
        for (int bb = 0; bb < 8; ++bb) {
            f0[bb] = (short)f2bf(b0[bb]);
            f1[bb] = (short)f2bf(b1[bb]);
        }
        acc0 = __builtin_amdgcn_mfma_f32_32x32x16_bf16(afrag, f0, acc0, 0, 0, 0);
        acc1 = __builtin_amdgcn_mfma_f32_32x32x16_bf16(afrag, f1, acc1, 0, 0, 0);
    }

    #pragma unroll
    for (int r = 0; r < 16; ++r) {
        int row = dblk + (r & 3) + 8 * (r >> 2) + 4 * hi;
        float bs = bias[n * 256 + row];
        size_t o = ((size_t)(n * 256 + row)) * HWPX + px0 + lo;
        out[o] = acc0[r] + bs;
        out[o + 32] = acc1[r] + bs;
    }
}

// ---------------------------------------------------------------------------
extern "C" void kernel_launch(void* const* d_in, const int* in_sizes, int n_in,
                              void* d_out, int out_size, void* d_ws, size_t ws_size,
                              hipStream_t stream) {
    const float* x      = (const float*)d_in[0];
    const int*   cls    = (const int*)d_in[1];
    const float* EK     = (const float*)d_in[2];
    const float* EB     = (const float*)d_in[3];
    const float* conv_w = (const float*)d_in[4];
    const float* conv_b = (const float*)d_in[5];
    float* out = (float*)d_out;

    float* wsf   = (float*)d_ws;
    float* part  = wsf;                  // 512*1056            = 540672 f
    float* S     = wsf + 540672;         // 64*1024             =  65536 f
    float* meanw = wsf + 606208;         // 64*32               =   2048 f
    float* bp    = wsf + 608256;         // 64*256              =  16384 f
    float* bias  = wsf + 624640;         // 8*256               =   2048 f
    ushort_t* M_bf = (ushort_t*)(wsf + 626688);  // 8*256*256 bf16 = 1 MiB

    const size_t xb_off   = 626688 * sizeof(float) + (size_t)8 * 256 * 256 * 2; // 3555328
    const size_t xb_bytes = (size_t)8 * HWPX * 256 * 2;                         // 64 MiB
    bool fast = ws_size >= xb_off + xb_bytes;
    ushort_t* xb = (ushort_t*)((char*)d_ws + xb_off);

    if (fast) {
        k_stats<true> <<<512, 512, 0, stream>>>(x, part, xb);
    } else {
        k_stats<false><<<512, 512, 0, stream>>>(x, part, (ushort_t*)M_bf);
    }
    k_chol   <<<64,   64, 0, stream>>>(part, S, meanw);
    k_compose<<<64,  256, 0, stream>>>(conv_w, EK, cls, S, meanw, M_bf, bp);
    k_bias   <<<8,   256, 0, stream>>>(conv_b, EB, cls, bp, bias);
    if (fast) {
        k_gemm_fast<<<1024, 512, 0, stream>>>(xb, M_bf, bias, out);
    } else {
        k_gemm_fb  <<<2048, 512, 0, stream>>>(x, M_bf, bias, out);
    }
}

// Round 3
// 140.221 us; speedup vs baseline: 1.4085x; 1.4085x over previous
//
#include <hip/hip_runtime.h>

typedef unsigned short ushort_t;
typedef __attribute__((ext_vector_type(8)))  short  short8;
typedef __attribute__((ext_vector_type(8)))  ushort_t ushort8;
typedef __attribute__((ext_vector_type(16))) float  f32x16;

#define HWPX 16384
#define EPSV 0.001f

__device__ __forceinline__ ushort_t f2bf(float f) {
    unsigned u = __builtin_bit_cast(unsigned, f);
    unsigned r = u + 0x7FFFu + ((u >> 16) & 1u);   // round-to-nearest-even
    return (ushort_t)(r >> 16);
}

__device__ __forceinline__ unsigned cvt_pk(float a, float b) {
    unsigned r;
    asm("v_cvt_pk_bf16_f32 %0, %1, %2" : "=v"(r) : "v"(a), "v"(b));
    return r;   // lo = bf16(a), hi = bf16(b)
}

// ===================== Pass 1 v3: coalesced stats + frag-ordered xb_t ======
// grid 512 = n(8) x g(8) x q(8); block 512 (8 waves).
// Per block: 32 ch (one group) x 2048 px, in 8 subtiles of 32ch x 256px.
// Stage fp32->bf16 into swizzled LDS tile; read back (a) cov A-frags via
// ds_read_b128, (b) B-fragment-ordered xb_t units (64 lanes x 16B = 1KB dense).
__device__ __forceinline__ void stats_load(float4 (&buf)[4], const float* xbase,
                                           int w, int col4, int sub) {
    #pragma unroll
    for (int rr = 0; rr < 4; ++rr)
        buf[rr] = *(const float4*)(xbase + (size_t)(w + rr * 8) * HWPX + sub * 256 + col4 * 4);
}

template<bool XBF>
__device__ __forceinline__ void stats_proc(float4 (&buf)[4], ushort_t* tile,
                                           f32x16& acc, float (&sm)[4],
                                           int n, int g, int q, int sub,
                                           int w, int l, int lo, int hi, int col4,
                                           ushort_t* __restrict__ xbt) {
    #pragma unroll
    for (int rr = 0; rr < 4; ++rr) {
        float4 v = buf[rr];
        sm[rr] += v.x + v.y + v.z + v.w;
        uint2 u;
        u.x = cvt_pk(v.x, v.y);
        u.y = cvt_pk(v.z, v.w);
        int row = w + rr * 8;
        int idx = (row * 256 + col4 * 4) ^ ((row & 7) << 3);   // ushort-idx XOR swizzle
        *(uint2*)&tile[idx] = u;
    }
    __syncthreads();
    // cov rank-k: A-frag = 8 consecutive px (k) of channel lo; same frag as A and B
    #pragma unroll
    for (int ks2 = 0; ks2 < 2; ++ks2) {
        int pidx = (lo * 256 + w * 32 + ks2 * 16 + hi * 8) ^ ((lo & 7) << 3);
        short8 f = *(const short8*)&tile[pidx];
        acc = __builtin_amdgcn_mfma_f32_32x32x16_bf16(f, f, acc, 0, 0, 0);
    }
    if (XBF) {
        // B-frag unit for px-block pb, ks = g*2+h: lane l holds
        // x[ks*16 + (l>>5)*8 + j][pb*32 + (l&31)], j=0..7
        int pb = q * 64 + sub * 8 + w;
        #pragma unroll
        for (int h = 0; h < 2; ++h) {
            ushort8 o;
            #pragma unroll
            for (int j = 0; j < 8; ++j) {
                int c = h * 16 + hi * 8 + j;
                o[j] = tile[(c * 256 + w * 32 + lo) ^ ((c & 7) << 3)];
            }
            *(ushort8*)(xbt + ((((size_t)(n * 512 + pb)) * 16 + g * 2 + h) * 64 + l) * 8) = o;
        }
    }
    __syncthreads();
}

template<bool XBF>
__global__ __launch_bounds__(512) void k_stats(const float* __restrict__ x,
                                               float* __restrict__ part,
                                               ushort_t* __restrict__ xbt) {
    __shared__ ushort_t tile[8192];       // 32ch x 256px bf16, swizzled (16KB)
    __shared__ float redc[8][1024];       // 32KB
    __shared__ float redm[32][64];        // 8KB
    int b = blockIdx.x;
    int n = b >> 6, g = (b >> 3) & 7, q = b & 7;
    int t = threadIdx.x, w = t >> 6, l = t & 63;
    int lo = l & 31, hi = l >> 5, col4 = l;
    const float* xbase = x + ((size_t)(n * 256 + g * 32)) * HWPX + q * 2048;

    f32x16 acc = {};
    float sm[4] = {0.f, 0.f, 0.f, 0.f};
    float4 bufA[4], bufB[4];

    stats_load(bufA, xbase, w, col4, 0);
    #pragma unroll 1
    for (int s2 = 0; s2 < 4; ++s2) {
        int sub0 = s2 * 2;
        stats_load(bufB, xbase, w, col4, sub0 + 1);
        stats_proc<XBF>(bufA, tile, acc, sm, n, g, q, sub0, w, l, lo, hi, col4, xbt);
        if (sub0 + 2 < 8) stats_load(bufA, xbase, w, col4, sub0 + 2);
        stats_proc<XBF>(bufB, tile, acc, sm, n, g, q, sub0 + 1, w, l, lo, hi, col4, xbt);
    }

    #pragma unroll
    for (int r = 0; r < 16; ++r) redc[w][l * 16 + r] = acc[r];
    #pragma unroll
    for (int rr = 0; rr < 4; ++rr) redm[w + rr * 8][col4] = sm[rr];
    __syncthreads();

    for (int i = t; i < 1024; i += 512) {
        float v = 0.f;
        #pragma unroll
        for (int ww = 0; ww < 8; ++ww) v += redc[ww][i];
        int ll = i >> 4, r = i & 15;
        int row = (r & 3) + 8 * (r >> 2) + 4 * (ll >> 5);   // C/D layout 32x32 (m74/m101)
        int col = ll & 31;
        part[(size_t)b * 1056 + row * 32 + col] = v;
    }
    if (t < 32) {
        float v = 0.f;
        for (int c = 0; c < 64; ++c) v += redm[t][c];
        part[(size_t)b * 1056 + 1024 + t] = v;
    }
}

// ===================== Pass 2: reduce, cov, cholesky, L^{-1} ===============
__global__ __launch_bounds__(64) void k_chol(const float* __restrict__ part,
                                             float* __restrict__ S,
                                             float* __restrict__ meanw) {
    int bg = blockIdx.x;
    int t = threadIdx.x;
    __shared__ float cov[1024];
    __shared__ float sums[32];
    __shared__ float A[32][33];
    __shared__ float Sl[32][33];

    for (int i = t; i < 1024; i += 64) {
        float v = 0.f;
        for (int q = 0; q < 8; ++q) v += part[(size_t)(bg * 8 + q) * 1056 + i];
        cov[i] = v;
    }
    if (t < 32) {
        float v = 0.f;
        for (int q = 0; q < 8; ++q) v += part[(size_t)(bg * 8 + q) * 1056 + 1024 + t];
        sums[t] = v;
    }
    __syncthreads();

    const float invHW = 1.0f / (float)HWPX;
    for (int i = t; i < 1024; i += 64) {
        int r = i >> 5, c = i & 31;
        float mr = sums[r] * invHW, mc = sums[c] * invHW;
        float cv = (cov[i] * invHW - mr * mc) * (1.0f - EPSV) + ((r == c) ? EPSV : 0.f);
        A[r][c] = cv;
    }
    __syncthreads();

    for (int k = 0; k < 32; ++k) {
        if (t == k) A[k][k] = sqrtf(A[k][k]);
        __syncthreads();
        if (t > k && t < 32) A[t][k] = A[t][k] / A[k][k];
        __syncthreads();
        if (t > k && t < 32) {
            float lik = A[t][k];
            for (int j = k + 1; j <= t; ++j) A[t][j] -= lik * A[j][k];
        }
        __syncthreads();
    }

    if (t < 32) {
        int c = t;
        for (int i = 0; i < c; ++i) Sl[i][c] = 0.f;
        Sl[c][c] = 1.0f / A[c][c];
        for (int i = c + 1; i < 32; ++i) {
            float s = 0.f;
            for (int j = c; j < i; ++j) s += A[i][j] * Sl[j][c];
            Sl[i][c] = -s / A[i][i];
        }
    }
    __syncthreads();

    for (int i = t; i < 1024; i += 64) S[(size_t)bg * 1024 + i] = Sl[i >> 5][i & 31];
    if (t < 32) meanw[bg * 32 + t] = sums[t] * invHW;
}

// ===================== Pass 3: compose M = (conv_w + K^T) * S ==============
// FRAG=true: emit M in A-fragment order M_t[n][dblk][ks][lane]*8.
template<bool FRAG>
__global__ __launch_bounds__(256) void k_compose(const float* __restrict__ conv_w,
                                                 const float* __restrict__ EK,
                                                 const int* __restrict__ cls_arr,
                                                 const float* __restrict__ S,
                                                 const float* __restrict__ meanw,
                                                 ushort_t* __restrict__ M_bf,
                                                 float* __restrict__ bp) {
    int bid = blockIdx.x;
    int n = bid >> 3, g = bid & 7;
    int d = threadIdx.x;
    __shared__ float Sl[1024];
    __shared__ float ml[32];
    for (int i = d; i < 1024; i += 256) Sl[i] = S[(size_t)bid * 1024 + i];
    if (d < 32) ml[d] = meanw[bid * 32 + d];
    __syncthreads();

    int cls = cls_arr[n];
    float a[32];
    #pragma unroll
    for (int c = 0; c < 32; ++c)
        a[c] = conv_w[d * 256 + g * 32 + c] +
               EK[(size_t)cls * 65536 + (size_t)(g * 32 + c) * 256 + d];

    float bpv = 0.f;
    ushort8 pk[4];
    #pragma unroll
    for (int cp = 0; cp < 32; ++cp) {
        float m = 0.f;
        #pragma unroll
        for (int c = cp; c < 32; ++c) m += a[c] * Sl[c * 32 + cp];  // S lower-tri
        bpv += m * ml[cp];
        pk[cp >> 3][cp & 7] = f2bf(m);
    }
    if (FRAG) {
        // pk[kk] covers channels cp = kk*8..+7 -> ks = g*2 + (kk>>1), lane = (d&31)+32*(kk&1)
        #pragma unroll
        for (int kk = 0; kk < 4; ++kk) {
            size_t u = (((size_t)(n * 8 + (d >> 5)) * 16) + g * 2 + (kk >> 1)) * 64
                       + (d & 31) + 32 * (kk & 1);
            *(ushort8*)(M_bf + u * 8) = pk[kk];
        }
    } else {
        ushort_t* dst = M_bf + ((size_t)(n * 256 + d)) * 256 + g * 32;
        #pragma unroll
        for (int k = 0; k < 4; ++k) *(ushort8*)(dst + k * 8) = pk[k];
    }
    bp[(size_t)(n * 8 + g) * 256 + d] = bpv;
}

// ===================== Pass 4: bias' = conv_b + eb - M*mean ================
__global__ __launch_bounds__(256) void k_bias(const float* __restrict__ conv_b,
                                              const float* __restrict__ EB,
                                              const int* __restrict__ cls_arr,
                                              const float* __restrict__ bp,
                                              float* __restrict__ bias) {
    int n = blockIdx.x, d = threadIdx.x;
    int cls = cls_arr[n];
    float v = conv_b[d] + EB[cls * 256 + d];
    #pragma unroll
    for (int g = 0; g < 8; ++g) v -= bp[(size_t)(n * 8 + g) * 256 + d];
    bias[n * 256 + d] = v;
}

// ===================== Pass 5 v3: out = M_t * xb_t + bias ==================
// grid 1024 = n(8) x pt(128, 128px each); block 512 (8 waves, wave = 32 d).
// All global loads are 64-lane x 16B = 1KB fully dense (fragment-ordered).
__global__ __launch_bounds__(512) void k_gemm_t(const ushort_t* __restrict__ xbt,
                                                const ushort_t* __restrict__ M_t,
                                                const float* __restrict__ bias,
                                                float* __restrict__ out) {
    int bid = blockIdx.x;
    int n = bid >> 7, pt = bid & 127;
    int t = threadIdx.x, w = t >> 6, l = t & 63, lo = l & 31, hi = l >> 5;
    int dblk = w * 32;

    const ushort_t* msrc = M_t + (((size_t)(n * 8 + w) * 16) * 64 + l) * 8;
    short8 a[16];
    #pragma unroll
    for (int ks = 0; ks < 16; ++ks)
        a[ks] = *(const short8*)(msrc + (size_t)ks * 64 * 8);

    float bsv[16];
    int rows[16];
    #pragma unroll
    for (int r = 0; r < 16; ++r) {
        rows[r] = dblk + (r & 3) + 8 * (r >> 2) + 4 * hi;   // C/D layout (m74/m101)
        bsv[r] = bias[n * 256 + rows[r]];
    }

    #pragma unroll 1
    for (int g4 = 0; g4 < 4; ++g4) {
        int pb = pt * 4 + g4;
        const ushort_t* bsrc = xbt + (((size_t)(n * 512 + pb) * 16) * 64 + l) * 8;
        f32x16 acc = {};
        #pragma unroll
        for (int ks = 0; ks < 16; ++ks) {
            short8 bf = *(const short8*)(bsrc + (size_t)ks * 64 * 8);
            acc = __builtin_amdgcn_mfma_f32_32x32x16_bf16(a[ks], bf, acc, 0, 0, 0);
        }
        int px = pb * 32 + lo;
        #pragma unroll
        for (int r = 0; r < 16; ++r)
            out[((size_t)(n * 256 + rows[r])) * HWPX + px] = acc[r] + bsv[r];
    }
}

// ===================== Fallback Pass 5: fp32 x, row-major M ================
__global__ __launch_bounds__(512) void k_gemm_fb(const float* __restrict__ x,
                                                 const ushort_t* __restrict__ M_bf,
                                                 const float* __restrict__ bias,
                                                 float* __restrict__ out) {
    int bid = blockIdx.x;
    int n = bid >> 8, pt = bid & 255;
    int px0 = pt * 64;
    int t = threadIdx.x, w = t >> 6, l = t & 63, lo = l & 31, hi = l >> 5;
    int dblk = w * 32;

    const ushort_t* Mrow = M_bf + ((size_t)(n * 256 + dblk + lo)) * 256;
    const float* xn = x + (size_t)n * 256 * HWPX;

    f32x16 acc0 = {}, acc1 = {};
    for (int ks = 0; ks < 16; ++ks) {
        int c0 = ks * 16 + hi * 8;
        short8 afrag = *(const short8*)(Mrow + c0);
        const float* xc = xn + (size_t)c0 * HWPX + px0 + lo;
        short8 f0, f1;
        #pragma unroll
        for (int bb = 0; bb < 8; ++bb) {
            f0[bb] = (short)f2bf(xc[(size_t)bb * HWPX]);
            f1[bb] = (short)f2bf(xc[(size_t)bb * HWPX + 32]);
        }
        acc0 = __builtin_amdgcn_mfma_f32_32x32x16_bf16(afrag, f0, acc0, 0, 0, 0);
        acc1 = __builtin_amdgcn_mfma_f32_32x32x16_bf16(afrag, f1, acc1, 0, 0, 0);
    }

    #pragma unroll
    for (int r = 0; r < 16; ++r) {
        int row = dblk + (r & 3) + 8 * (r >> 2) + 4 * hi;
        float bs = bias[n * 256 + row];
        size_t o = ((size_t)(n * 256 + row)) * HWPX + px0 + lo;
        out[o] = acc0[r] + bs;
        out[o + 32] = acc1[r] + bs;
    }
}

// ===========================================================================
extern "C" void kernel_launch(void* const* d_in, const int* in_sizes, int n_in,
                              void* d_out, int out_size, void* d_ws, size_t ws_size,
                              hipStream_t stream) {
    const float* x      = (const float*)d_in[0];
    const int*   cls    = (const int*)d_in[1];
    const float* EK     = (const float*)d_in[2];
    const float* EB     = (const float*)d_in[3];
    const float* conv_w = (const float*)d_in[4];
    const float* conv_b = (const float*)d_in[5];
    float* out = (float*)d_out;

    float* wsf   = (float*)d_ws;
    float* part  = wsf;                  // 512*1056            = 540672 f
    float* S     = wsf + 540672;         // 64*1024             =  65536 f
    float* meanw = wsf + 606208;         // 64*32               =   2048 f
    float* bp    = wsf + 608256;         // 64*256              =  16384 f
    float* bias  = wsf + 624640;         // 8*256               =   2048 f
    ushort_t* M_bf = (ushort_t*)(wsf + 626688);  // 8*256*256 bf16 = 1 MiB

    const size_t xb_off   = 626688 * sizeof(float) + (size_t)8 * 256 * 256 * 2; // 3555328
    const size_t xb_bytes = (size_t)8 * HWPX * 256 * 2;                         // 64 MiB
    bool fast = ws_size >= xb_off + xb_bytes;
    ushort_t* xb = (ushort_t*)((char*)d_ws + xb_off);

    if (fast) {
        k_stats<true>  <<<512, 512, 0, stream>>>(x, part, xb);
        k_chol         <<<64,   64, 0, stream>>>(part, S, meanw);
        k_compose<true><<<64,  256, 0, stream>>>(conv_w, EK, cls, S, meanw, M_bf, bp);
        k_bias         <<<8,   256, 0, stream>>>(conv_b, EB, cls, bp, bias);
        k_gemm_t       <<<1024, 512, 0, stream>>>(xb, M_bf, bias, out);
    } else {
        k_stats<false>  <<<512, 512, 0, stream>>>(x, part, (ushort_t*)M_bf);
        k_chol          <<<64,   64, 0, stream>>>(part, S, meanw);
        k_compose<false><<<64,  256, 0, stream>>>(conv_w, EK, cls, S, meanw, M_bf, bp);
        k_bias          <<<8,   256, 0, stream>>>(conv_b, EB, cls, bp, bias);
        k_gemm_fb       <<<2048, 512, 0, stream>>>(x, M_bf, bias, out);
    }
}

// Round 4
// 130.828 us; speedup vs baseline: 1.5096x; 1.0718x over previous
//
#include <hip/hip_runtime.h>

typedef unsigned short ushort_t;
typedef __attribute__((ext_vector_type(8)))  short  short8;
typedef __attribute__((ext_vector_type(8)))  ushort_t ushort8;
typedef __attribute__((ext_vector_type(16))) float  f32x16;

#define HWPX 16384
#define EPSV 0.001f

__device__ __forceinline__ ushort_t f2bf(float f) {
    unsigned u = __builtin_bit_cast(unsigned, f);
    unsigned r = u + 0x7FFFu + ((u >> 16) & 1u);   // round-to-nearest-even
    return (ushort_t)(r >> 16);
}

__device__ __forceinline__ unsigned cvt_pk(float a, float b) {
    unsigned r;
    asm("v_cvt_pk_bf16_f32 %0, %1, %2" : "=v"(r) : "v"(a), "v"(b));
    return r;   // lo = bf16(a), hi = bf16(b)
}

__device__ __forceinline__ void gld_lds16(const ushort_t* g, ushort_t* l) {
    __builtin_amdgcn_global_load_lds(
        (const __attribute__((address_space(1))) unsigned int*)g,
        (__attribute__((address_space(3))) unsigned int*)l, 16, 0, 0);
}

// ===================== Pass 1 v4: coalesced stats + frag-ordered xb_t ======
// grid 512 = n(8) x g(8) x q(8); block 512 (8 waves).
// Per block: 32 ch x 2048 px in 8 subtiles of 32ch x 256px. Double-buffered
// LDS tile, ONE raw barrier per subtile (no vmcnt drain -> prefetch lives).
__device__ __forceinline__ void stats_load(float4 (&buf)[4], const float* xbase,
                                           int w, int col4, int sub) {
    #pragma unroll
    for (int rr = 0; rr < 4; ++rr)
        buf[rr] = *(const float4*)(xbase + (size_t)(w + rr * 8) * HWPX + sub * 256 + col4 * 4);
}

template<bool XBF>
__global__ __launch_bounds__(512) void k_stats(const float* __restrict__ x,
                                               float* __restrict__ part,
                                               ushort_t* __restrict__ xbt) {
    __shared__ ushort_t tile[16384];      // 2 x (32ch x 256px) bf16, swizzled (32KB)
    __shared__ float redc[8][1024];       // 32KB
    __shared__ float redm[32][64];        // 8KB
    int b = blockIdx.x;
    int n = b >> 6, g = (b >> 3) & 7, q = b & 7;
    int t = threadIdx.x, w = t >> 6, l = t & 63;
    int lo = l & 31, hi = l >> 5, col4 = l;
    const float* xbase = x + ((size_t)(n * 256 + g * 32)) * HWPX + q * 2048;

    f32x16 acc = {};
    float sm[4] = {0.f, 0.f, 0.f, 0.f};
    float4 buf[4], nxt[4];

    stats_load(buf, xbase, w, col4, 0);
    #pragma unroll 1
    for (int s = 0; s < 8; ++s) {
        if (s < 7) stats_load(nxt, xbase, w, col4, s + 1);
        ushort_t* tl = tile + (s & 1) * 8192;
        #pragma unroll
        for (int rr = 0; rr < 4; ++rr) {
            float4 v = buf[rr];
            sm[rr] += v.x + v.y + v.z + v.w;
            uint2 u;
            u.x = cvt_pk(v.x, v.y);
            u.y = cvt_pk(v.z, v.w);
            int row = w + rr * 8;
            int idx = (row * 256 + col4 * 4) ^ ((row & 7) << 3);   // ushort-idx swizzle
            *(uint2*)&tl[idx] = u;
        }
        asm volatile("s_waitcnt lgkmcnt(0)" ::: "memory");
        __builtin_amdgcn_s_barrier();
        __builtin_amdgcn_sched_barrier(0);
        // cov rank-k: frag = 8 consecutive px of channel lo (same frag as A and B)
        #pragma unroll
        for (int ks2 = 0; ks2 < 2; ++ks2) {
            int pidx = (lo * 256 + w * 32 + ks2 * 16 + hi * 8) ^ ((lo & 7) << 3);
            short8 f = *(const short8*)&tl[pidx];
            acc = __builtin_amdgcn_mfma_f32_32x32x16_bf16(f, f, acc, 0, 0, 0);
        }
        if (XBF) {
            // B-frag unit (pb, ks=g*2+h): lane l holds x[ks*16+(l>>5)*8+j][pb*32+(l&31)]
            int pb = q * 64 + s * 8 + w;
            #pragma unroll
            for (int h = 0; h < 2; ++h) {
                ushort8 o;
                #pragma unroll
                for (int j = 0; j < 8; ++j) {
                    int c = h * 16 + hi * 8 + j;
                    o[j] = tl[(c * 256 + w * 32 + lo) ^ ((c & 7) << 3)];
                }
                *(ushort8*)(xbt + ((((size_t)(n * 512 + pb)) * 16 + g * 2 + h) * 64 + l) * 8) = o;
            }
        }
        #pragma unroll
        for (int rr = 0; rr < 4; ++rr) buf[rr] = nxt[rr];
    }

    #pragma unroll
    for (int r = 0; r < 16; ++r) redc[w][l * 16 + r] = acc[r];
    #pragma unroll
    for (int rr = 0; rr < 4; ++rr) redm[w + rr * 8][col4] = sm[rr];
    __syncthreads();

    for (int i = t; i < 1024; i += 512) {
        float v = 0.f;
        #pragma unroll
        for (int ww = 0; ww < 8; ++ww) v += redc[ww][i];
        int ll = i >> 4, r = i & 15;
        int row = (r & 3) + 8 * (r >> 2) + 4 * (ll >> 5);   // C/D layout 32x32 (m74/m101)
        int col = ll & 31;
        part[(size_t)b * 1056 + row * 32 + col] = v;
    }
    if (t < 32) {
        float v = 0.f;
        for (int c = 0; c < 64; ++c) v += redm[t][c];
        part[(size_t)b * 1056 + 1024 + t] = v;
    }
}

// ===================== Pass 2 (merged): reduce+cholesky+inverse+compose ====
// grid 64 = n*8+g; block 256.  FRAG=true -> M in A-fragment order.
template<bool FRAG>
__global__ __launch_bounds__(256) void k_prep(const float* __restrict__ part,
                                              const float* __restrict__ conv_w,
                                              const float* __restrict__ EK,
                                              const int* __restrict__ cls_arr,
                                              ushort_t* __restrict__ M_bf,
                                              float* __restrict__ bp) {
    int bid = blockIdx.x;
    int n = bid >> 3, g = bid & 7;
    int t = threadIdx.x;
    __shared__ float cov[1024];
    __shared__ float sums[32];
    __shared__ float A[32][33];
    __shared__ float Sinv[32][33];
    __shared__ float ml[32];

    for (int i = t; i < 1024; i += 256) {
        float v = 0.f;
        for (int q = 0; q < 8; ++q) v += part[(size_t)(bid * 8 + q) * 1056 + i];
        cov[i] = v;
    }
    if (t < 32) {
        float v = 0.f;
        for (int q = 0; q < 8; ++q) v += part[(size_t)(bid * 8 + q) * 1056 + 1024 + t];
        sums[t] = v;
    }
    __syncthreads();

    const float invHW = 1.0f / (float)HWPX;
    for (int i = t; i < 1024; i += 256) {
        int r = i >> 5, c = i & 31;
        float mr = sums[r] * invHW, mc = sums[c] * invHW;
        A[r][c] = (cov[i] * invHW - mr * mc) * (1.0f - EPSV) + ((r == c) ? EPSV : 0.f);
    }
    if (t < 32) ml[t] = sums[t] * invHW;
    __syncthreads();

    // right-looking cholesky (lower tri of A becomes L)
    for (int k = 0; k < 32; ++k) {
        if (t == k) A[k][k] = sqrtf(A[k][k]);
        __syncthreads();
        if (t > k && t < 32) A[t][k] = A[t][k] / A[k][k];
        __syncthreads();
        if (t > k && t < 32) {
            float lik = A[t][k];
            for (int j = k + 1; j <= t; ++j) A[t][j] -= lik * A[j][k];
        }
        __syncthreads();
    }
    // Sinv = L^{-1}, one column per lane
    if (t < 32) {
        int c = t;
        for (int i = 0; i < c; ++i) Sinv[i][c] = 0.f;
        Sinv[c][c] = 1.0f / A[c][c];
        for (int i = c + 1; i < 32; ++i) {
            float s = 0.f;
            for (int j = c; j < i; ++j) s += A[i][j] * Sinv[j][c];
            Sinv[i][c] = -s / A[i][i];
        }
    }
    __syncthreads();

    // compose: thread = output row d
    int d = t;
    int cls = cls_arr[n];
    float a[32];
    #pragma unroll
    for (int c = 0; c < 32; ++c)
        a[c] = conv_w[d * 256 + g * 32 + c] +
               EK[(size_t)cls * 65536 + (size_t)(g * 32 + c) * 256 + d];

    float bpv = 0.f;
    ushort8 pk[4];
    #pragma unroll
    for (int cp = 0; cp < 32; ++cp) {
        float m = 0.f;
        #pragma unroll
        for (int c = cp; c < 32; ++c) m += a[c] * Sinv[c][cp];  // lower-tri
        bpv += m * ml[cp];
        pk[cp >> 3][cp & 7] = f2bf(m);
    }
    if (FRAG) {
        #pragma unroll
        for (int kk = 0; kk < 4; ++kk) {
            size_t u = (((size_t)(n * 8 + (d >> 5)) * 16) + g * 2 + (kk >> 1)) * 64
                       + (d & 31) + 32 * (kk & 1);
            *(ushort8*)(M_bf + u * 8) = pk[kk];
        }
    } else {
        ushort_t* dst = M_bf + ((size_t)(n * 256 + d)) * 256 + g * 32;
        #pragma unroll
        for (int k = 0; k < 4; ++k) *(ushort8*)(dst + k * 8) = pk[k];
    }
    bp[(size_t)(n * 8 + g) * 256 + d] = bpv;
}

// ===================== Pass 3: bias' = conv_b + eb - M*mean ================
__global__ __launch_bounds__(256) void k_bias(const float* __restrict__ conv_b,
                                              const float* __restrict__ EB,
                                              const int* __restrict__ cls_arr,
                                              const float* __restrict__ bp,
                                              float* __restrict__ bias) {
    int n = blockIdx.x, d = threadIdx.x;
    int cls = cls_arr[n];
    float v = conv_b[d] + EB[cls * 256 + d];
    #pragma unroll
    for (int g = 0; g < 8; ++g) v -= bp[(size_t)(n * 8 + g) * 256 + d];
    bias[n * 256 + d] = v;
}

// ===================== Pass 4 v4: out = M_t * xb_t + bias (LDS-staged B) ===
// grid 512 = n(8) x pt(64, 256px each); block 512 (8 waves, wave = 32 rows).
// B-frags staged once per block into LDS dbuf via global_load_lds; raw
// s_barrier + counted vmcnt(16) so stores/prefetch stay in flight.
__global__ __launch_bounds__(512, 4) void k_gemm_s(const ushort_t* __restrict__ xbt,
                                                   const ushort_t* __restrict__ M_t,
                                                   const float* __restrict__ bias,
                                                   float* __restrict__ out) {
    __shared__ ushort_t bstage[16384];   // 2 x 16KB
    int bid = blockIdx.x;
    int n = bid >> 6, pt = bid & 63;
    int t = threadIdx.x, w = t >> 6, l = t & 63, lo = l & 31, hi = l >> 5;
    int dblk = w * 32;

    const ushort_t* msrc = M_t + (((size_t)(n * 8 + w) * 16) * 64 + l) * 8;
    short8 a[16];
    #pragma unroll
    for (int ks = 0; ks < 16; ++ks)
        a[ks] = *(const short8*)(msrc + (size_t)ks * 512);

    float bsv[16];
    #pragma unroll
    for (int r = 0; r < 16; ++r)
        bsv[r] = bias[n * 256 + dblk + (r & 3) + 8 * (r >> 2) + 4 * hi];

    const ushort_t* xsrc = xbt + (size_t)(n * 512 + pt * 8) * 8192;   // 8 pb x 16KB

    // prologue: stage pb=0 into buf0
    gld_lds16(xsrc + w * 1024 + l * 8,       bstage + w * 1024);
    gld_lds16(xsrc + w * 1024 + 512 + l * 8, bstage + w * 1024 + 512);
    asm volatile("s_waitcnt vmcnt(0)" ::: "memory");
    __builtin_amdgcn_s_barrier();
    __builtin_amdgcn_sched_barrier(0);

    #pragma unroll 1
    for (int pb = 0; pb < 8; ++pb) {
        ushort_t* bufc = bstage + (pb & 1) * 8192;
        if (pb < 7) {   // stage pb+1 into other buffer (readers of it are 2 phases back)
            ushort_t* bufn = bstage + ((pb + 1) & 1) * 8192;
            const ushort_t* src = xsrc + (size_t)(pb + 1) * 8192;
            gld_lds16(src + w * 1024 + l * 8,       bufn + w * 1024);
            gld_lds16(src + w * 1024 + 512 + l * 8, bufn + w * 1024 + 512);
        }
        __builtin_amdgcn_sched_barrier(0);

        f32x16 acc = {};
        #pragma unroll
        for (int ks = 0; ks < 16; ++ks) {
            short8 bf = *(const short8*)(bufc + ks * 512 + l * 8);
            acc = __builtin_amdgcn_mfma_f32_32x32x16_bf16(a[ks], bf, acc, 0, 0, 0);
        }

        int px = (pt * 8 + pb) * 32 + lo;
        #pragma unroll
        for (int r = 0; r < 16; ++r) {
            int row = dblk + (r & 3) + 8 * (r >> 2) + 4 * hi;
            out[((size_t)(n * 256 + row)) * HWPX + px] = acc[r] + bsv[r];
        }

        if (pb < 7) {
            // own stage(pb+1) done (16 stores of this pb still in flight)
            asm volatile("s_waitcnt vmcnt(16)" ::: "memory");
            __builtin_amdgcn_sched_barrier(0);
            __builtin_amdgcn_s_barrier();
            __builtin_amdgcn_sched_barrier(0);
        }
    }
}

// ===================== Fallback Pass 4: fp32 x, row-major M ================
__global__ __launch_bounds__(512) void k_gemm_fb(const float* __restrict__ x,
                                                 const ushort_t* __restrict__ M_bf,
                                                 const float* __restrict__ bias,
                                                 float* __restrict__ out) {
    int bid = blockIdx.x;
    int n = bid >> 8, pt = bid & 255;
    int px0 = pt * 64;
    int t = threadIdx.x, w = t >> 6, l = t & 63, lo = l & 31, hi = l >> 5;
    int dblk = w * 32;

    const ushort_t* Mrow = M_bf + ((size_t)(n * 256 + dblk + lo)) * 256;
    const float* xn = x + (size_t)n * 256 * HWPX;

    f32x16 acc0 = {}, acc1 = {};
    for (int ks = 0; ks < 16; ++ks) {
        int c0 = ks * 16 + hi * 8;
        short8 afrag = *(const short8*)(Mrow + c0);
        const float* xc = xn + (size_t)c0 * HWPX + px0 + lo;
        short8 f0, f1;
        #pragma unroll
        for (int bb = 0; bb < 8; ++bb) {
            f0[bb] = (short)f2bf(xc[(size_t)bb * HWPX]);
            f1[bb] = (short)f2bf(xc[(size_t)bb * HWPX + 32]);
        }
        acc0 = __builtin_amdgcn_mfma_f32_32x32x16_bf16(afrag, f0, acc0, 0, 0, 0);
        acc1 = __builtin_amdgcn_mfma_f32_32x32x16_bf16(afrag, f1, acc1, 0, 0, 0);
    }

    #pragma unroll
    for (int r = 0; r < 16; ++r) {
        int row = dblk + (r & 3) + 8 * (r >> 2) + 4 * hi;
        float bs = bias[n * 256 + row];
        size_t o = ((size_t)(n * 256 + row)) * HWPX + px0 + lo;
        out[o] = acc0[r] + bs;
        out[o + 32] = acc1[r] + bs;
    }
}

// ===========================================================================
extern "C" void kernel_launch(void* const* d_in, const int* in_sizes, int n_in,
                              void* d_out, int out_size, void* d_ws, size_t ws_size,
                              hipStream_t stream) {
    const float* x      = (const float*)d_in[0];
    const int*   cls    = (const int*)d_in[1];
    const float* EK     = (const float*)d_in[2];
    const float* EB     = (const float*)d_in[3];
    const float* conv_w = (const float*)d_in[4];
    const float* conv_b = (const float*)d_in[5];
    float* out = (float*)d_out;

    float* wsf   = (float*)d_ws;
    float* part  = wsf;                          // 512*1056 = 540672 f
    float* bp    = wsf + 540672;                 // 16384 f
    float* bias  = wsf + 557056;                 // 2048 f
    ushort_t* M  = (ushort_t*)(wsf + 559104);    // 8*256*256 bf16 = 1 MiB

    const size_t xb_off   = 559104 * sizeof(float) + (size_t)8 * 256 * 256 * 2; // 3284992
    const size_t xb_bytes = (size_t)8 * HWPX * 256 * 2;                         // 64 MiB
    bool fast = ws_size >= xb_off + xb_bytes;
    ushort_t* xb = (ushort_t*)((char*)d_ws + xb_off);

    if (fast) {
        k_stats<true>  <<<512, 512, 0, stream>>>(x, part, xb);
        k_prep<true>   <<<64,  256, 0, stream>>>(part, conv_w, EK, cls, M, bp);
        k_bias         <<<8,   256, 0, stream>>>(conv_b, EB, cls, bp, bias);
        k_gemm_s       <<<512, 512, 0, stream>>>(xb, M, bias, out);
    } else {
        k_stats<false> <<<512, 512, 0, stream>>>(x, part, M);
        k_prep<false>  <<<64,  256, 0, stream>>>(part, conv_w, EK, cls, M, bp);
        k_bias         <<<8,   256, 0, stream>>>(conv_b, EB, cls, bp, bias);
        k_gemm_fb      <<<2048, 512, 0, stream>>>(x, M, bias, out);
    }
}

// Round 5
// 129.495 us; speedup vs baseline: 1.5252x; 1.0103x over previous
//
#include <hip/hip_runtime.h>

typedef unsigned short ushort_t;
typedef __attribute__((ext_vector_type(8)))  short  short8;
typedef __attribute__((ext_vector_type(8)))  ushort_t ushort8;
typedef __attribute__((ext_vector_type(16))) float  f32x16;

#define HWPX 16384
#define EPSV 0.001f

#define WSYNC do { asm volatile("s_waitcnt lgkmcnt(0)" ::: "memory"); \
                   __builtin_amdgcn_sched_barrier(0); } while (0)

__device__ __forceinline__ ushort_t f2bf(float f) {
    unsigned u = __builtin_bit_cast(unsigned, f);
    unsigned r = u + 0x7FFFu + ((u >> 16) & 1u);   // round-to-nearest-even
    return (ushort_t)(r >> 16);
}

__device__ __forceinline__ unsigned cvt_pk(float a, float b) {
    unsigned r;
    asm("v_cvt_pk_bf16_f32 %0, %1, %2" : "=v"(r) : "v"(a), "v"(b));
    return r;   // lo = bf16(a), hi = bf16(b)
}

__device__ __forceinline__ void gld_lds16(const ushort_t* g, ushort_t* l) {
    __builtin_amdgcn_global_load_lds(
        (const __attribute__((address_space(1))) unsigned int*)g,
        (__attribute__((address_space(3))) unsigned int*)l, 16, 0, 0);
}

// ===================== Pass 1 v5: coalesced stats + frag-ordered xb_t ======
// grid 512 = n(8) x g(8) x q(8); block 512 (8 waves). LDS 40KB (tile/redc
// unioned) -> 3 blocks/CU. One raw barrier per subtile, no vmcnt drain.
__device__ __forceinline__ void stats_load(float4 (&buf)[4], const float* xbase,
                                           int w, int col4, int sub) {
    #pragma unroll
    for (int rr = 0; rr < 4; ++rr)
        buf[rr] = *(const float4*)(xbase + (size_t)(w + rr * 8) * HWPX + sub * 256 + col4 * 4);
}

template<bool XBF>
__global__ __launch_bounds__(512, 2) void k_stats(const float* __restrict__ x,
                                                  float* __restrict__ part,
                                                  ushort_t* __restrict__ xbt) {
    __shared__ char smraw[40960];         // union: tile(32KB) | redc(32KB); +redm 8KB
    ushort_t* tile = (ushort_t*)smraw;    // 2 x (32ch x 256px) bf16, swizzled
    float (*redc)[1024] = (float(*)[1024])smraw;
    float (*redm)[64] = (float(*)[64])(smraw + 32768);
    int b = blockIdx.x;
    int n = b >> 6, g = (b >> 3) & 7, q = b & 7;
    int t = threadIdx.x, w = t >> 6, l = t & 63;
    int lo = l & 31, hi = l >> 5, col4 = l;
    const float* xbase = x + ((size_t)(n * 256 + g * 32)) * HWPX + q * 2048;

    f32x16 acc = {};
    float sm[4] = {0.f, 0.f, 0.f, 0.f};
    float4 buf[4], nxt[4];

    stats_load(buf, xbase, w, col4, 0);
    #pragma unroll 1
    for (int s = 0; s < 8; ++s) {
        if (s < 7) stats_load(nxt, xbase, w, col4, s + 1);
        ushort_t* tl = tile + (s & 1) * 8192;
        #pragma unroll
        for (int rr = 0; rr < 4; ++rr) {
            float4 v = buf[rr];
            sm[rr] += v.x + v.y + v.z + v.w;
            uint2 u;
            u.x = cvt_pk(v.x, v.y);
            u.y = cvt_pk(v.z, v.w);
            int row = w + rr * 8;
            int idx = (row * 256 + col4 * 4) ^ ((row & 7) << 3);   // ushort-idx swizzle
            *(uint2*)&tl[idx] = u;
        }
        asm volatile("s_waitcnt lgkmcnt(0)" ::: "memory");
        __builtin_amdgcn_s_barrier();
        __builtin_amdgcn_sched_barrier(0);
        // cov rank-k: frag = 8 consecutive px of channel lo (same frag as A and B)
        #pragma unroll
        for (int ks2 = 0; ks2 < 2; ++ks2) {
            int pidx = (lo * 256 + w * 32 + ks2 * 16 + hi * 8) ^ ((lo & 7) << 3);
            short8 f = *(const short8*)&tl[pidx];
            acc = __builtin_amdgcn_mfma_f32_32x32x16_bf16(f, f, acc, 0, 0, 0);
        }
        if (XBF) {
            // B-frag unit (pb, ks=g*2+h): lane l holds x[ks*16+(l>>5)*8+j][pb*32+(l&31)]
            int pb = q * 64 + s * 8 + w;
            #pragma unroll
            for (int h = 0; h < 2; ++h) {
                ushort8 o;
                #pragma unroll
                for (int j = 0; j < 8; ++j) {
                    int c = h * 16 + hi * 8 + j;
                    o[j] = tl[(c * 256 + w * 32 + lo) ^ ((c & 7) << 3)];
                }
                *(ushort8*)(xbt + ((((size_t)(n * 512 + pb)) * 16 + g * 2 + h) * 64 + l) * 8) = o;
            }
        }
        #pragma unroll
        for (int rr = 0; rr < 4; ++rr) buf[rr] = nxt[rr];
    }

    __syncthreads();    // tile reads done everywhere before redc overwrites it
    #pragma unroll
    for (int r = 0; r < 16; ++r) redc[w][l * 16 + r] = acc[r];
    #pragma unroll
    for (int rr = 0; rr < 4; ++rr) redm[w + rr * 8][col4] = sm[rr];
    __syncthreads();

    for (int i = t; i < 1024; i += 512) {
        float v = 0.f;
        #pragma unroll
        for (int ww = 0; ww < 8; ++ww) v += redc[ww][i];
        int ll = i >> 4, r = i & 15;
        int row = (r & 3) + 8 * (r >> 2) + 4 * (ll >> 5);   // C/D layout 32x32 (m74/m101)
        int col = ll & 31;
        part[(size_t)b * 1056 + row * 32 + col] = v;
    }
    if (t < 32) {
        float v = 0.f;
        for (int c = 0; c < 64; ++c) v += redm[t][c];
        part[(size_t)b * 1056 + 1024 + t] = v;
    }
}

// ===================== Pass 2: reduce + wave0-cholesky + compose ===========
// grid 64 = n*8+g; block 256.  FRAG=true -> M in A-fragment order.
template<bool FRAG>
__global__ __launch_bounds__(256, 2) void k_prep(const float* __restrict__ part,
                                                 const float* __restrict__ conv_w,
                                                 const float* __restrict__ EK,
                                                 const int* __restrict__ cls_arr,
                                                 ushort_t* __restrict__ M_bf,
                                                 float* __restrict__ bp) {
    int bid = blockIdx.x;
    int n = bid >> 3, g = bid & 7;
    int t = threadIdx.x;
    __shared__ float cov[1024];
    __shared__ float sums[32];
    __shared__ float A[32][33];
    __shared__ float Sinv[32][33];
    __shared__ float ml[32];
    __shared__ float cw[256][33];   // conv_w slice, padded (conflict-free column read)

    // coalesced conv_w stage: 8 lanes per row, 4 rows-groups per wave pass
    for (int i = 0; i < 8; ++i) {
        int r = i * 32 + (t >> 3);
        float4 v = *(const float4*)(conv_w + r * 256 + g * 32 + (t & 7) * 4);
        #pragma unroll
        for (int e = 0; e < 4; ++e) cw[r][(t & 7) * 4 + e] = ((float*)&v)[e];
    }

    for (int i = t; i < 1024; i += 256) {
        float v = 0.f;
        for (int q = 0; q < 8; ++q) v += part[(size_t)(bid * 8 + q) * 1056 + i];
        cov[i] = v;
    }
    if (t < 32) {
        float v = 0.f;
        for (int q = 0; q < 8; ++q) v += part[(size_t)(bid * 8 + q) * 1056 + 1024 + t];
        sums[t] = v;
    }
    __syncthreads();

    const float invHW = 1.0f / (float)HWPX;
    for (int i = t; i < 1024; i += 256) {
        int r = i >> 5, c = i & 31;
        float mr = sums[r] * invHW, mc = sums[c] * invHW;
        A[r][c] = (cov[i] * invHW - mr * mc) * (1.0f - EPSV) + ((r == c) ? EPSV : 0.f);
    }
    if (t < 32) ml[t] = sums[t] * invHW;
    __syncthreads();

    // wave 0 only: right-looking cholesky + L^{-1}, lockstep sync (no s_barrier)
    if (t < 64) {
        for (int k = 0; k < 32; ++k) {
            if (t == k) A[k][k] = sqrtf(A[k][k]);
            WSYNC;
            if (t > k && t < 32) A[t][k] = A[t][k] / A[k][k];
            WSYNC;
            if (t > k && t < 32) {
                float lik = A[t][k];
                for (int j = k + 1; j <= t; ++j) A[t][j] -= lik * A[j][k];
            }
            WSYNC;
        }
        if (t < 32) {   // Sinv = L^{-1}, one column per lane
            int c = t;
            for (int i = 0; i < c; ++i) Sinv[i][c] = 0.f;
            Sinv[c][c] = 1.0f / A[c][c];
            for (int i = c + 1; i < 32; ++i) {
                float s = 0.f;
                for (int j = c; j < i; ++j) s += A[i][j] * Sinv[j][c];
                Sinv[i][c] = -s / A[i][i];
            }
        }
    }
    __syncthreads();

    // compose: thread = output row d
    int d = t;
    int cls = cls_arr[n];
    float a[32];
    #pragma unroll
    for (int c = 0; c < 32; ++c)
        a[c] = cw[d][c] + EK[(size_t)cls * 65536 + (size_t)(g * 32 + c) * 256 + d];

    float bpv = 0.f;
    ushort8 pk[4];
    #pragma unroll
    for (int cp = 0; cp < 32; ++cp) {
        float m = 0.f;
        #pragma unroll
        for (int c = cp; c < 32; ++c) m += a[c] * Sinv[c][cp];  // lower-tri
        bpv += m * ml[cp];
        pk[cp >> 3][cp & 7] = f2bf(m);
    }
    if (FRAG) {
        #pragma unroll
        for (int kk = 0; kk < 4; ++kk) {
            size_t u = (((size_t)(n * 8 + (d >> 5)) * 16) + g * 2 + (kk >> 1)) * 64
                       + (d & 31) + 32 * (kk & 1);
            *(ushort8*)(M_bf + u * 8) = pk[kk];
        }
    } else {
        ushort_t* dst = M_bf + ((size_t)(n * 256 + d)) * 256 + g * 32;
        #pragma unroll
        for (int k = 0; k < 4; ++k) *(ushort8*)(dst + k * 8) = pk[k];
    }
    bp[(size_t)(n * 8 + g) * 256 + d] = bpv;
}

// ===================== Pass 3: bias' = conv_b + eb - M*mean ================
__global__ __launch_bounds__(256) void k_bias(const float* __restrict__ conv_b,
                                              const float* __restrict__ EB,
                                              const int* __restrict__ cls_arr,
                                              const float* __restrict__ bp,
                                              float* __restrict__ bias) {
    int n = blockIdx.x, d = threadIdx.x;
    int cls = cls_arr[n];
    float v = conv_b[d] + EB[cls * 256 + d];
    #pragma unroll
    for (int g = 0; g < 8; ++g) v -= bp[(size_t)(n * 8 + g) * 256 + d];
    bias[n * 256 + d] = v;
}

// ===================== Pass 4 v5: out = M_t * xb_t + bias ==================
// grid 512 = n(8) x pt(64, 256px each); block 512 (8 waves, wave = 32 rows).
// Triple-buffered LDS B-stage (global_load_lds), counted vmcnt(18), raw
// barriers; (512,2) so the persistent A-frags can NOT spill.
__global__ __launch_bounds__(512, 2) void k_gemm_s(const ushort_t* __restrict__ xbt,
                                                   const ushort_t* __restrict__ M_t,
                                                   const float* __restrict__ bias,
                                                   float* __restrict__ out) {
    __shared__ ushort_t bstage[24576];   // 3 x 16KB
    int bid = blockIdx.x;
    int n = bid >> 6, pt = bid & 63;
    int t = threadIdx.x, w = t >> 6, l = t & 63, lo = l & 31, hi = l >> 5;
    int dblk = w * 32;

    const ushort_t* msrc = M_t + (((size_t)(n * 8 + w) * 16) * 64 + l) * 8;
    short8 a[16];
    #pragma unroll
    for (int ks = 0; ks < 16; ++ks)
        a[ks] = *(const short8*)(msrc + (size_t)ks * 512);

    float bsv[16];
    #pragma unroll
    for (int r = 0; r < 16; ++r)
        bsv[r] = bias[n * 256 + dblk + (r & 3) + 8 * (r >> 2) + 4 * hi];

    const ushort_t* xsrc = xbt + (size_t)(n * 512 + pt * 8) * 8192;   // 8 pb x 16KB

    // prologue: stage pb=0,1
    #pragma unroll
    for (int p = 0; p < 2; ++p) {
        const ushort_t* src = xsrc + (size_t)p * 8192;
        gld_lds16(src + w * 1024 + l * 8,       bstage + p * 8192 + w * 1024);
        gld_lds16(src + w * 1024 + 512 + l * 8, bstage + p * 8192 + w * 1024 + 512);
    }
    asm volatile("s_waitcnt vmcnt(2)" ::: "memory");   // pb=0 landed (pb=1 in flight)
    __builtin_amdgcn_s_barrier();
    __builtin_amdgcn_sched_barrier(0);

    #pragma unroll 1
    for (int pb = 0; pb < 8; ++pb) {
        ushort_t* bufc = bstage + (pb % 3) * 8192;
        if (pb + 2 < 8) {
            ushort_t* bufn = bstage + ((pb + 2) % 3) * 8192;
            const ushort_t* src = xsrc + (size_t)(pb + 2) * 8192;
            gld_lds16(src + w * 1024 + l * 8,       bufn + w * 1024);
            gld_lds16(src + w * 1024 + 512 + l * 8, bufn + w * 1024 + 512);
        }
        __builtin_amdgcn_sched_barrier(0);

        f32x16 acc = {};
        #pragma unroll
        for (int ks = 0; ks < 16; ++ks) {
            short8 bf = *(const short8*)(bufc + ks * 512 + l * 8);
            acc = __builtin_amdgcn_mfma_f32_32x32x16_bf16(a[ks], bf, acc, 0, 0, 0);
        }

        int px = (pt * 8 + pb) * 32 + lo;
        #pragma unroll
        for (int r = 0; r < 16; ++r) {
            int row = dblk + (r & 3) + 8 * (r >> 2) + 4 * hi;
            out[((size_t)(n * 256 + row)) * HWPX + px] = acc[r] + bsv[r];
        }

        if (pb < 7) {
            // keep 16 stores(this pb) + 2 stage(pb+2) in flight; force stage(pb+1)
            // and older stores complete.
            asm volatile("s_waitcnt vmcnt(18)" ::: "memory");
            __builtin_amdgcn_sched_barrier(0);
            __builtin_amdgcn_s_barrier();
            __builtin_amdgcn_sched_barrier(0);
        }
    }
}

// ===================== Fallback Pass 4: fp32 x, row-major M ================
__global__ __launch_bounds__(512, 2) void k_gemm_fb(const float* __restrict__ x,
                                                    const ushort_t* __restrict__ M_bf,
                                                    const float* __restrict__ bias,
                                                    float* __restrict__ out) {
    int bid = blockIdx.x;
    int n = bid >> 8, pt = bid & 255;
    int px0 = pt * 64;
    int t = threadIdx.x, w = t >> 6, l = t & 63, lo = l & 31, hi = l >> 5;
    int dblk = w * 32;

    const ushort_t* Mrow = M_bf + ((size_t)(n * 256 + dblk + lo)) * 256;
    const float* xn = x + (size_t)n * 256 * HWPX;

    f32x16 acc0 = {}, acc1 = {};
    for (int ks = 0; ks < 16; ++ks) {
        int c0 = ks * 16 + hi * 8;
        short8 afrag = *(const short8*)(Mrow + c0);
        const float* xc = xn + (size_t)c0 * HWPX + px0 + lo;
        short8 f0, f1;
        #pragma unroll
        for (int bb = 0; bb < 8; ++bb) {
            f0[bb] = (short)f2bf(xc[(size_t)bb * HWPX]);
            f1[bb] = (short)f2bf(xc[(size_t)bb * HWPX + 32]);
        }
        acc0 = __builtin_amdgcn_mfma_f32_32x32x16_bf16(afrag, f0, acc0, 0, 0, 0);
        acc1 = __builtin_amdgcn_mfma_f32_32x32x16_bf16(afrag, f1, acc1, 0, 0, 0);
    }

    #pragma unroll
    for (int r = 0; r < 16; ++r) {
        int row = dblk + (r & 3) + 8 * (r >> 2) + 4 * hi;
        float bs = bias[n * 256 + row];
        size_t o = ((size_t)(n * 256 + row)) * HWPX + px0 + lo;
        out[o] = acc0[r] + bs;
        out[o + 32] = acc1[r] + bs;
    }
}

// ===========================================================================
extern "C" void kernel_launch(void* const* d_in, const int* in_sizes, int n_in,
                              void* d_out, int out_size, void* d_ws, size_t ws_size,
                              hipStream_t stream) {
    const float* x      = (const float*)d_in[0];
    const int*   cls    = (const int*)d_in[1];
    const float* EK     = (const float*)d_in[2];
    const float* EB     = (const float*)d_in[3];
    const float* conv_w = (const float*)d_in[4];
    const float* conv_b = (const float*)d_in[5];
    float* out = (float*)d_out;

    float* wsf   = (float*)d_ws;
    float* part  = wsf;                          // 512*1056 = 540672 f
    float* bp    = wsf + 540672;                 // 16384 f
    float* bias  = wsf + 557056;                 // 2048 f
    ushort_t* M  = (ushort_t*)(wsf + 559104);    // 8*256*256 bf16 = 1 MiB

    const size_t xb_off   = 559104 * sizeof(float) + (size_t)8 * 256 * 256 * 2; // 3284992
    const size_t xb_bytes = (size_t)8 * HWPX * 256 * 2;                         // 64 MiB
    bool fast = ws_size >= xb_off + xb_bytes;
    ushort_t* xb = (ushort_t*)((char*)d_ws + xb_off);

    if (fast) {
        k_stats<true>  <<<512, 512, 0, stream>>>(x, part, xb);
        k_prep<true>   <<<64,  256, 0, stream>>>(part, conv_w, EK, cls, M, bp);
        k_bias         <<<8,   256, 0, stream>>>(conv_b, EB, cls, bp, bias);
        k_gemm_s       <<<512, 512, 0, stream>>>(xb, M, bias, out);
    } else {
        k_stats<false> <<<512, 512, 0, stream>>>(x, part, M);
        k_prep<false>  <<<64,  256, 0, stream>>>(part, conv_w, EK, cls, M, bp);
        k_bias         <<<8,   256, 0, stream>>>(conv_b, EB, cls, bp, bias);
        k_gemm_fb      <<<2048, 512, 0, stream>>>(x, M, bias, out);
    }
}